// Round 1
// baseline (144.807 us; speedup 1.0000x reference)
//
#include <hip/hip_runtime.h>
#include <cstdint>
#include <cstddef>

#define SEQ 8192
#define EMB 1024
#define DH  128
#define NSPLIT 4
#define KVBLK 64
#define QBLK 64

typedef __bf16 bf16x8 __attribute__((ext_vector_type(8)));
typedef float  f32x4  __attribute__((ext_vector_type(4)));

// fp32 -> bf16 round-to-nearest-even (inputs are sane; no NaN handling needed)
__device__ __forceinline__ unsigned short f2bf(float f) {
  uint32_t u = __builtin_bit_cast(uint32_t, f);
  u += 0x7FFFu + ((u >> 16) & 1u);
  return (unsigned short)(u >> 16);
}

// async global->LDS, 16B per lane; dst must be wave-uniform (HW adds lane*16)
#define GLD_LDS16(gsrc, ldst) \
  __builtin_amdgcn_global_load_lds((__attribute__((address_space(1))) void*)(gsrc), \
                                   (__attribute__((address_space(3))) void*)(ldst), 16, 0, 0)

// ---------------------------------------------------------------------------
// Kernel 1: QKV projection. grid=(64,3), block=256 (4 waves, 2x2 of 64x64).
// C tile 128x128, BK=32, fp32->bf16 conversion during staging.
// y==0 -> Q (pre-scaled by 1/sqrt(128)), y==1 -> K, y==2 -> V^T (transposed out)
// ---------------------------------------------------------------------------
__global__ __launch_bounds__(256) void qkv_kernel(
    const float* __restrict__ x,
    const float* __restrict__ wq, const float* __restrict__ wk, const float* __restrict__ wv,
    unsigned short* __restrict__ qs, unsigned short* __restrict__ ks,
    unsigned short* __restrict__ vt)
{
  // stride 40 (80B): bank(r)=20r%32 hits 8 distinct banks -> 2-way (free)
  __shared__ unsigned short As[128][40];
  __shared__ unsigned short Ws[128][40];
  __shared__ unsigned short T[128][136];   // epilogue re-vectorize / transpose

  const int t    = threadIdx.x;
  const int lane = t & 63;
  const int wid  = t >> 6;
  const int wr   = wid >> 1, wc = wid & 1;
  const int l15  = lane & 15;
  const int lg   = lane >> 4;
  const int row0 = blockIdx.x * 128;
  const int which = blockIdx.y;
  const float* w = (which == 0) ? wq : ((which == 1) ? wk : wv);

  f32x4 acc[4][4] = {};

  for (int k0 = 0; k0 < EMB; k0 += 32) {
    // stage A: x[row0 + (t>>1)][k0 + (t&1)*16 .. +15], convert to bf16
    {
      const int ar = t >> 1;
      const int ac = (t & 1) * 16;
      const float* src = x + (size_t)(row0 + ar) * EMB + k0 + ac;
#pragma unroll
      for (int i = 0; i < 4; ++i) {
        float4 v = *reinterpret_cast<const float4*>(src + i * 4);
        ushort4 pk = { f2bf(v.x), f2bf(v.y), f2bf(v.z), f2bf(v.w) };
        *reinterpret_cast<ushort4*>(&As[ar][ac + i * 4]) = pk;
      }
    }
    // stage W transposed: Ws[n][kk] = w[k0+kk][n]
    {
      const int kk = t >> 3;
      const int nn = (t & 7) * 16;
      const float* src = w + (size_t)(k0 + kk) * DH + nn;
#pragma unroll
      for (int i = 0; i < 4; ++i) {
        float4 v = *reinterpret_cast<const float4*>(src + i * 4);
        Ws[nn + i * 4 + 0][kk] = f2bf(v.x);
        Ws[nn + i * 4 + 1][kk] = f2bf(v.y);
        Ws[nn + i * 4 + 2][kk] = f2bf(v.z);
        Ws[nn + i * 4 + 3][kk] = f2bf(v.w);
      }
    }
    __syncthreads();

    bf16x8 af[4], bq[4];
#pragma unroll
    for (int mt = 0; mt < 4; ++mt)
      af[mt] = *reinterpret_cast<const bf16x8*>(&As[wr * 64 + mt * 16 + l15][lg * 8]);
#pragma unroll
    for (int nt = 0; nt < 4; ++nt)
      bq[nt] = *reinterpret_cast<const bf16x8*>(&Ws[wc * 64 + nt * 16 + l15][lg * 8]);
#pragma unroll
    for (int mt = 0; mt < 4; ++mt)
#pragma unroll
      for (int nt = 0; nt < 4; ++nt)
        acc[mt][nt] = __builtin_amdgcn_mfma_f32_16x16x32_bf16(af[mt], bq[nt], acc[mt][nt], 0, 0, 0);
    __syncthreads();
  }

  const float scale = (which == 0) ? 0.08838834764831845f : 1.0f;
  // D-layout (verified): col = lane&15, row = (lane>>4)*4 + reg
  if (which < 2) {
#pragma unroll
    for (int mt = 0; mt < 4; ++mt)
#pragma unroll
      for (int nt = 0; nt < 4; ++nt)
#pragma unroll
        for (int j = 0; j < 4; ++j)
          T[wr * 64 + mt * 16 + lg * 4 + j][wc * 64 + nt * 16 + l15] = f2bf(acc[mt][nt][j] * scale);
  } else {
    // transpose into T[d][seq]
#pragma unroll
    for (int mt = 0; mt < 4; ++mt)
#pragma unroll
      for (int nt = 0; nt < 4; ++nt)
#pragma unroll
        for (int j = 0; j < 4; ++j)
          T[wc * 64 + nt * 16 + l15][wr * 64 + mt * 16 + lg * 4 + j] = f2bf(acc[mt][nt][j]);
  }
  __syncthreads();

  // cooperative vectorized store: thread t -> T[t>>1][(t&1)*64 .. +63]
  const int srow  = t >> 1;
  const int scol0 = (t & 1) * 64;
  unsigned short* dst = (which == 0) ? qs : ((which == 1) ? ks : vt);
#pragma unroll
  for (int i = 0; i < 8; ++i) {
    uint4 v = *reinterpret_cast<const uint4*>(&T[srow][scol0 + i * 8]);
    size_t off;
    if (which < 2) off = (size_t)(row0 + srow) * DH + scol0 + i * 8;      // [seq][d]
    else           off = (size_t)srow * SEQ + row0 + scol0 + i * 8;      // [d][seq]
    *reinterpret_cast<uint4*>(dst + off) = v;
  }
}

// ---------------------------------------------------------------------------
// Kernel 2: flash attention partials. grid=(128, NSPLIT), block=256 (4 waves).
// Each wave: 16 q-rows, full D=128. KV chunk = 64 keys/iter, 32 iters.
// K LDS [64][128] bf16 + V^T LDS [128][64] bf16, both XOR-swizzled via
// pre-swizzled global_load_lds sources. P per-wave LDS [16][72] (padded).
// ---------------------------------------------------------------------------
__global__ __launch_bounds__(256, 2) void attn_kernel(
    const unsigned short* __restrict__ qs, const unsigned short* __restrict__ ks,
    const unsigned short* __restrict__ vt,
    float* __restrict__ Op, float* __restrict__ ml)
{
  __shared__ unsigned short Ks[64 * 128];
  __shared__ unsigned short Vt[128 * 64];
  __shared__ unsigned short Pl[4][16 * 72];

  const int t    = threadIdx.x;
  const int lane = t & 63;
  const int wid  = t >> 6;
  const int l15  = lane & 15;
  const int lg   = lane >> 4;
  const int qt   = blockIdx.x;
  const int sp   = blockIdx.y;
  const int qrow = qt * QBLK + wid * 16;

  // hoist Q fragments (Q already scaled by 1/sqrt(128))
  bf16x8 qf[4];
  {
    const unsigned short* qp = qs + (size_t)(qrow + l15) * DH;
#pragma unroll
    for (int c = 0; c < 4; ++c)
      qf[c] = *reinterpret_cast<const bf16x8*>(qp + c * 32 + lg * 8);
  }

  float m[4] = { -__builtin_inff(), -__builtin_inff(), -__builtin_inff(), -__builtin_inff() };
  float l[4] = { 0.f, 0.f, 0.f, 0.f };
  f32x4 O[8] = {};

  const char* ksc = reinterpret_cast<const char*>(ks);
  const char* vtc = reinterpret_cast<const char*>(vt);
  char* ksl = reinterpret_cast<char*>(Ks);
  char* vtl = reinterpret_cast<char*>(Vt);
  unsigned short* pw = &Pl[wid][0];

  for (int ic = 0; ic < (SEQ / NSPLIT) / KVBLK; ++ic) {
    const int kv0 = sp * (SEQ / NSPLIT) + ic * KVBLK;

    // ---- stage K [64][128]B-swz and V^T [128][64]B-swz, 16B/lane async ----
#pragma unroll
    for (int i = 0; i < 4; ++i) {
      int bidx = i * 256 + wid * 64 + lane;
      int key = bidx >> 4, blk = bidx & 15;
      const char* src = ksc + (size_t)(kv0 + key) * 256 + ((blk * 16) ^ ((key & 7) << 4));
      GLD_LDS16(src, ksl + i * 4096 + wid * 1024);
    }
#pragma unroll
    for (int i = 0; i < 4; ++i) {
      int bidx = i * 256 + wid * 64 + lane;
      int d = bidx >> 3, kb = bidx & 7;
      const char* src = vtc + (size_t)d * (SEQ * 2) + (size_t)kv0 * 2 + ((kb * 16) ^ ((d & 7) << 4));
      GLD_LDS16(src, vtl + i * 4096 + wid * 1024);
    }
    __syncthreads();   // drains vmcnt(0) -> tiles ready

    // ---- QK^T: S[16 q][64 key], A=Q frags, B=K rows (swizzled read) ----
    f32x4 S[4];
    const f32x4 z = { 0.f, 0.f, 0.f, 0.f };
#pragma unroll
    for (int nt = 0; nt < 4; ++nt) {
      S[nt] = z;
      const int key = nt * 16 + l15;
#pragma unroll
      for (int c = 0; c < 4; ++c) {
        int doff = (c * 64 + lg * 16) ^ ((key & 7) << 4);
        bf16x8 kb = *reinterpret_cast<const bf16x8*>(ksl + key * 256 + doff);
        S[nt] = __builtin_amdgcn_mfma_f32_16x16x32_bf16(qf[c], kb, S[nt], 0, 0, 0);
      }
    }

    // ---- online softmax (wave-parallel; row = lg*4+j, key lanes = l15) ----
    float mn[4], corr[4];
#pragma unroll
    for (int j = 0; j < 4; ++j) {
      float tm = fmaxf(fmaxf(S[0][j], S[1][j]), fmaxf(S[2][j], S[3][j]));
#pragma unroll
      for (int off = 8; off >= 1; off >>= 1)
        tm = fmaxf(tm, __shfl_xor(tm, off, 64));
      mn[j]   = fmaxf(m[j], tm);
      corr[j] = __expf(m[j] - mn[j]);   // expf(-inf)=0 on first tile
      m[j]    = mn[j];
    }
#pragma unroll
    for (int j = 0; j < 4; ++j) {
      float s0 = __expf(S[0][j] - mn[j]);
      float s1 = __expf(S[1][j] - mn[j]);
      float s2 = __expf(S[2][j] - mn[j]);
      float s3 = __expf(S[3][j] - mn[j]);
      float rsum = s0 + s1 + s2 + s3;
#pragma unroll
      for (int off = 8; off >= 1; off >>= 1)
        rsum += __shfl_xor(rsum, off, 64);
      l[j] = l[j] * corr[j] + rsum;
      const int r = lg * 4 + j;
      pw[r * 72 +  0 + l15] = f2bf(s0);
      pw[r * 72 + 16 + l15] = f2bf(s1);
      pw[r * 72 + 32 + l15] = f2bf(s2);
      pw[r * 72 + 48 + l15] = f2bf(s3);
    }
    // rescale O by correction factor
#pragma unroll
    for (int nt = 0; nt < 8; ++nt)
#pragma unroll
      for (int j = 0; j < 4; ++j)
        O[nt][j] *= corr[j];

    asm volatile("s_waitcnt lgkmcnt(0)" ::: "memory");  // P writes -> P reads (same wave)

    // ---- PV: O[16][128] += P[16][64] * V[64][128]; B from V^T (swz read) ----
#pragma unroll
    for (int kk = 0; kk < 2; ++kk) {
      bf16x8 pa = *reinterpret_cast<const bf16x8*>(&pw[l15 * 72 + kk * 32 + lg * 8]);
#pragma unroll
      for (int nt = 0; nt < 8; ++nt) {
        const int d = nt * 16 + l15;
        int koff = (kk * 64 + lg * 16) ^ ((d & 7) << 4);
        bf16x8 vb = *reinterpret_cast<const bf16x8*>(vtl + d * 128 + koff);
        O[nt] = __builtin_amdgcn_mfma_f32_16x16x32_bf16(pa, vb, O[nt], 0, 0, 0);
      }
    }
    __syncthreads();   // protect LDS tiles before next stage
  }

  // ---- write partials: unnormalized O, plus (m, l) stats ----
  float* Obase = Op + ((size_t)sp * SEQ + qrow) * DH;
#pragma unroll
  for (int nt = 0; nt < 8; ++nt)
#pragma unroll
    for (int j = 0; j < 4; ++j)
      Obase[(size_t)(lg * 4 + j) * DH + nt * 16 + l15] = O[nt][j];
  if (l15 == 0) {
#pragma unroll
    for (int j = 0; j < 4; ++j) {
      ml[(size_t)sp * (2 * SEQ) + (qrow + lg * 4 + j)]       = m[j];
      ml[(size_t)sp * (2 * SEQ) + SEQ + (qrow + lg * 4 + j)] = l[j];
    }
  }
}

// ---------------------------------------------------------------------------
// Kernel 3: combine the NSPLIT partials via log-sum-exp merge.
// ---------------------------------------------------------------------------
__global__ __launch_bounds__(128) void combine_kernel(
    const float* __restrict__ Op, const float* __restrict__ ml, float* __restrict__ out)
{
  const int s = blockIdx.x;
  const int d = threadIdx.x;
  float mv[NSPLIT], lv[NSPLIT];
  float M = -__builtin_inff();
#pragma unroll
  for (int i = 0; i < NSPLIT; ++i) {
    mv[i] = ml[(size_t)i * (2 * SEQ) + s];
    lv[i] = ml[(size_t)i * (2 * SEQ) + SEQ + s];
    M = fmaxf(M, mv[i]);
  }
  float den = 0.f, num = 0.f;
#pragma unroll
  for (int i = 0; i < NSPLIT; ++i) {
    float w = __expf(mv[i] - M);
    den += w * lv[i];
    num += w * Op[((size_t)i * SEQ + s) * DH + d];
  }
  out[(size_t)s * DH + d] = num / den;
}

// ---------------------------------------------------------------------------
extern "C" void kernel_launch(void* const* d_in, const int* in_sizes, int n_in,
                              void* d_out, int out_size, void* d_ws, size_t ws_size,
                              hipStream_t stream) {
  const float* x  = (const float*)d_in[0];
  const float* wq = (const float*)d_in[1];
  const float* wk = (const float*)d_in[2];
  const float* wv = (const float*)d_in[3];
  float* out = (float*)d_out;

  char* ws = (char*)d_ws;
  unsigned short* qs = (unsigned short*)(ws);                       // [8192][128] bf16, pre-scaled
  unsigned short* ks = (unsigned short*)(ws + 2u * 1024 * 1024);    // [8192][128] bf16
  unsigned short* vt = (unsigned short*)(ws + 4u * 1024 * 1024);    // [128][8192] bf16 (V^T)
  float* Op = (float*)(ws + 6u * 1024 * 1024);                      // [NSPLIT][8192][128] f32
  float* ml = (float*)(ws + 6u * 1024 * 1024 + (size_t)NSPLIT * SEQ * DH * 4); // [NSPLIT][2][8192]

  qkv_kernel<<<dim3(SEQ / 128, 3), 256, 0, stream>>>(x, wq, wk, wv, qs, ks, vt);
  attn_kernel<<<dim3(SEQ / QBLK, NSPLIT), 256, 0, stream>>>(qs, ks, vt, Op, ml);
  combine_kernel<<<SEQ, 128, 0, stream>>>(Op, ml, out);
}

// Round 2
// 109.657 us; speedup vs baseline: 1.3205x; 1.3205x over previous
//
#include <hip/hip_runtime.h>
#include <cstdint>
#include <cstddef>

#define SEQ 8192
#define EMB 1024
#define DH  128

typedef __bf16 bf16x8 __attribute__((ext_vector_type(8)));
typedef __bf16 bf16x2 __attribute__((ext_vector_type(2)));
typedef float  f32x4  __attribute__((ext_vector_type(4)));
typedef float  f32x16 __attribute__((ext_vector_type(16)));
typedef uint32_t u32x4 __attribute__((ext_vector_type(4)));

// Q pre-scale: log2(e)/sqrt(128) -> scores land in log2 domain, softmax uses v_exp_f32 directly
#define QSCALE 0.12751744416But
#undef QSCALE
static constexpr float QSCALE = (float)(1.4426950408889634 / 11.313708498984760);

// fp32 -> bf16 round-to-nearest-even
__device__ __forceinline__ unsigned short f2bf(float f) {
  uint32_t u = __builtin_bit_cast(uint32_t, f);
  u += 0x7FFFu + ((u >> 16) & 1u);
  return (unsigned short)(u >> 16);
}

// async global->LDS, 16B per lane; dst wave-uniform base (HW adds lane*16)
#define GLD_LDS16(gsrc, ldst) \
  __builtin_amdgcn_global_load_lds((__attribute__((address_space(1))) void*)(gsrc), \
                                   (__attribute__((address_space(3))) void*)(ldst), 16, 0, 0)

// ---------------------------------------------------------------------------
// Kernel 1: QKV projection. grid=(64,3), block=256 (4 waves, 2x2 of 64x64).
// y==0 -> Q (pre-scaled by log2e/sqrt(128)), y==1 -> K, y==2 -> V^T [d][seq]
// ---------------------------------------------------------------------------
__global__ __launch_bounds__(256) void qkv_kernel(
    const float* __restrict__ x,
    const float* __restrict__ wq, const float* __restrict__ wk, const float* __restrict__ wv,
    unsigned short* __restrict__ qs, unsigned short* __restrict__ ks,
    unsigned short* __restrict__ vt)
{
  __shared__ unsigned short As[128][40];
  __shared__ unsigned short Ws[128][40];
  __shared__ unsigned short T[128][136];

  const int t    = threadIdx.x;
  const int lane = t & 63;
  const int wid  = t >> 6;
  const int wr   = wid >> 1, wc = wid & 1;
  const int l15  = lane & 15;
  const int lg   = lane >> 4;
  const int row0 = blockIdx.x * 128;
  const int which = blockIdx.y;
  const float* w = (which == 0) ? wq : ((which == 1) ? wk : wv);

  f32x4 acc[4][4] = {};

  for (int k0 = 0; k0 < EMB; k0 += 32) {
    {
      const int ar = t >> 1;
      const int ac = (t & 1) * 16;
      const float* src = x + (size_t)(row0 + ar) * EMB + k0 + ac;
#pragma unroll
      for (int i = 0; i < 4; ++i) {
        float4 v = *reinterpret_cast<const float4*>(src + i * 4);
        ushort4 pk = { f2bf(v.x), f2bf(v.y), f2bf(v.z), f2bf(v.w) };
        *reinterpret_cast<ushort4*>(&As[ar][ac + i * 4]) = pk;
      }
    }
    {
      const int kk = t >> 3;
      const int nn = (t & 7) * 16;
      const float* src = w + (size_t)(k0 + kk) * DH + nn;
#pragma unroll
      for (int i = 0; i < 4; ++i) {
        float4 v = *reinterpret_cast<const float4*>(src + i * 4);
        Ws[nn + i * 4 + 0][kk] = f2bf(v.x);
        Ws[nn + i * 4 + 1][kk] = f2bf(v.y);
        Ws[nn + i * 4 + 2][kk] = f2bf(v.z);
        Ws[nn + i * 4 + 3][kk] = f2bf(v.w);
      }
    }
    __syncthreads();

    bf16x8 af[4], bq[4];
#pragma unroll
    for (int mt = 0; mt < 4; ++mt)
      af[mt] = *reinterpret_cast<const bf16x8*>(&As[wr * 64 + mt * 16 + l15][lg * 8]);
#pragma unroll
    for (int nt = 0; nt < 4; ++nt)
      bq[nt] = *reinterpret_cast<const bf16x8*>(&Ws[wc * 64 + nt * 16 + l15][lg * 8]);
#pragma unroll
    for (int mt = 0; mt < 4; ++mt)
#pragma unroll
      for (int nt = 0; nt < 4; ++nt)
        acc[mt][nt] = __builtin_amdgcn_mfma_f32_16x16x32_bf16(af[mt], bq[nt], acc[mt][nt], 0, 0, 0);
    __syncthreads();
  }

  const float scale = (which == 0) ? QSCALE : 1.0f;
  if (which < 2) {
#pragma unroll
    for (int mt = 0; mt < 4; ++mt)
#pragma unroll
      for (int nt = 0; nt < 4; ++nt)
#pragma unroll
        for (int j = 0; j < 4; ++j)
          T[wr * 64 + mt * 16 + lg * 4 + j][wc * 64 + nt * 16 + l15] = f2bf(acc[mt][nt][j] * scale);
  } else {
#pragma unroll
    for (int mt = 0; mt < 4; ++mt)
#pragma unroll
      for (int nt = 0; nt < 4; ++nt)
#pragma unroll
        for (int j = 0; j < 4; ++j)
          T[wc * 64 + nt * 16 + l15][wr * 64 + mt * 16 + lg * 4 + j] = f2bf(acc[mt][nt][j]);
  }
  __syncthreads();

  const int srow  = t >> 1;
  const int scol0 = (t & 1) * 64;
  unsigned short* dst = (which == 0) ? qs : ((which == 1) ? ks : vt);
#pragma unroll
  for (int i = 0; i < 8; ++i) {
    uint4 v = *reinterpret_cast<const uint4*>(&T[srow][scol0 + i * 8]);
    size_t off;
    if (which < 2) off = (size_t)(row0 + srow) * DH + scol0 + i * 8;
    else           off = (size_t)srow * SEQ + row0 + scol0 + i * 8;
    *reinterpret_cast<uint4*>(dst + off) = v;
  }
}

// ---------------------------------------------------------------------------
// Kernel 2: flash attention partials, m214-style 8-wave swapped-QK^T.
// grid=(SEQ/256, NS), block=512 (8 waves x 32 q-rows). KVBLK=64, dbuf LDS.
// Per lane: q = lane&31; S^T rows = keys crow(r,hi)=(r&3)+8(r>>2)+4hi.
// ---------------------------------------------------------------------------
template <int NS>
__global__ __launch_bounds__(512, 2) void attn_kernel(
    const unsigned short* __restrict__ qs, const unsigned short* __restrict__ ks,
    const unsigned short* __restrict__ vt,
    float* __restrict__ Op, float* __restrict__ ml)
{
  __shared__ unsigned short Ks[2][64 * 128];   // [key][d], XOR-swizzled rows
  __shared__ unsigned short Vt[2][128 * 64];   // [d][key], XOR-swizzled rows

  const int t    = threadIdx.x;
  const int lane = t & 63;
  const int wid  = t >> 6;
  const int l31  = lane & 31;
  const int hi   = lane >> 5;
  const int swz  = (lane & 7) << 4;
  const int q0   = blockIdx.x * 256 + wid * 32;
  const int sp   = blockIdx.y;

  // hoist Q fragments: qf[ds] = Q[q0+l31][ds*16 + hi*8 .. +7]
  bf16x8 qf[8];
  {
    const unsigned short* qp = qs + (size_t)(q0 + l31) * DH + hi * 8;
#pragma unroll
    for (int ds = 0; ds < 8; ++ds)
      qf[ds] = *reinterpret_cast<const bf16x8*>(qp + ds * 16);
  }

  float m = -__builtin_inff();
  float l = 0.f;
  f32x16 O[4] = {};   // O[nt]: col d = nt*32+l31, rows q = crow(r,hi)

  const char* ksc = (const char*)ks;
  const char* vtc = (const char*)vt;
  char* ksl = (char*)&Ks[0][0];
  char* vtl = (char*)&Vt[0][0];

  constexpr int CHUNK = SEQ / NS;
  constexpr int NT = CHUNK / 64;
  const int kv_base = sp * CHUNK;

  // wave issues 2 K + 2 V global_load_lds (16B/lane) per tile
  auto STAGE = [&](int buf, int it) {
    const int kv0 = kv_base + it * 64;
#pragma unroll
    for (int rr = 0; rr < 2; ++rr) {
      int bidx = rr * 512 + t;
      int key = bidx >> 4, blk = bidx & 15;
      const char* src = ksc + (size_t)(kv0 + key) * 256 + ((blk * 16) ^ ((key & 7) << 4));
      GLD_LDS16(src, ksl + buf * 16384 + rr * 8192 + wid * 1024);
    }
#pragma unroll
    for (int rr = 0; rr < 2; ++rr) {
      int bidx = rr * 512 + t;
      int d = bidx >> 3, kb = bidx & 7;
      const char* src = vtc + (size_t)d * (SEQ * 2) + (size_t)kv0 * 2 + ((kb * 16) ^ ((d & 7) << 4));
      GLD_LDS16(src, vtl + buf * 16384 + rr * 8192 + wid * 1024);
    }
  };

  // build 2 bf16x8 A-frags (16 keys each) from one f32x16 P-tile (32 keys)
  auto build2 = [&](const f32x16& P, bf16x8* fr) {
    uint32_t c[8];
#pragma unroll
    for (int i = 0; i < 8; ++i) {
      bf16x2 b2; b2[0] = (__bf16)P[2 * i]; b2[1] = (__bf16)P[2 * i + 1];
      c[i] = __builtin_bit_cast(uint32_t, b2);
    }
    uint32_t r0 = __shfl_xor(c[0], 32, 64), r1 = __shfl_xor(c[1], 32, 64);
    uint32_t r2 = __shfl_xor(c[2], 32, 64), r3 = __shfl_xor(c[3], 32, 64);
    u32x4 w0;
    w0[0] = hi ? r2 : c[0];
    w0[1] = hi ? r3 : c[1];
    w0[2] = hi ? c[2] : r0;
    w0[3] = hi ? c[3] : r1;
    uint32_t r4 = __shfl_xor(c[4], 32, 64), r5 = __shfl_xor(c[5], 32, 64);
    uint32_t r6 = __shfl_xor(c[6], 32, 64), r7 = __shfl_xor(c[7], 32, 64);
    u32x4 w1;
    w1[0] = hi ? r6 : c[4];
    w1[1] = hi ? r7 : c[5];
    w1[2] = hi ? c[6] : r4;
    w1[3] = hi ? c[7] : r5;
    fr[0] = __builtin_bit_cast(bf16x8, w0);
    fr[1] = __builtin_bit_cast(bf16x8, w1);
  };

  STAGE(0, 0);

  int cur = 0;
  for (int it = 0; it < NT; ++it) {
    if (it + 1 < NT) {
      STAGE(cur ^ 1, it + 1);
      asm volatile("s_waitcnt vmcnt(4)" ::: "memory");   // my 4 loads for tile `it` done
    } else {
      asm volatile("s_waitcnt vmcnt(0)" ::: "memory");
    }
    __builtin_amdgcn_s_barrier();
    asm volatile("" ::: "memory");

    const char* kbase = ksl + cur * 16384;
    const char* vbase = vtl + cur * 16384;

    // ---- swapped QK^T: S^T = mfma(A=K, B=Q). 16 MFMA. ----
    f32x16 S0 = {}, S1 = {};
    __builtin_amdgcn_s_setprio(1);
#pragma unroll
    for (int ds = 0; ds < 8; ++ds) {
      bf16x8 ka = *reinterpret_cast<const bf16x8*>(kbase + l31 * 256 + ((ds * 32 + hi * 16) ^ swz));
      S0 = __builtin_amdgcn_mfma_f32_32x32x16_bf16(ka, qf[ds], S0, 0, 0, 0);
    }
#pragma unroll
    for (int ds = 0; ds < 8; ++ds) {
      bf16x8 ka = *reinterpret_cast<const bf16x8*>(kbase + 8192 + l31 * 256 + ((ds * 32 + hi * 16) ^ swz));
      S1 = __builtin_amdgcn_mfma_f32_32x32x16_bf16(ka, qf[ds], S1, 0, 0, 0);
    }
    __builtin_amdgcn_s_setprio(0);

    // ---- in-register online softmax (log2 domain), defer-max THR=11 ----
    float pm;
    {
      float a = S0[0];
#pragma unroll
      for (int r = 1; r < 16; ++r) a = fmaxf(a, S0[r]);
#pragma unroll
      for (int r = 0; r < 16; ++r) a = fmaxf(a, S1[r]);
      pm = fmaxf(a, __shfl_xor(a, 32, 64));
    }
    if (__any(pm > m + 11.0f)) {         // rare: ~first tile only
      float mn = fmaxf(m, pm);
      float corr = __builtin_amdgcn_exp2f(m - mn);   // exp2(-inf)=0 on first tile
      m = mn;
      l *= corr;
#pragma unroll
      for (int r = 0; r < 16; ++r) {
        float cr = __shfl(corr, (r & 3) + 8 * (r >> 2) + 4 * hi, 64);
#pragma unroll
        for (int nt = 0; nt < 4; ++nt) O[nt][r] *= cr;
      }
    }
    float rsum = 0.f;
#pragma unroll
    for (int r = 0; r < 16; ++r) { S0[r] = __builtin_amdgcn_exp2f(S0[r] - m); rsum += S0[r]; }
#pragma unroll
    for (int r = 0; r < 16; ++r) { S1[r] = __builtin_amdgcn_exp2f(S1[r] - m); rsum += S1[r]; }
    l += rsum + __shfl_xor(rsum, 32, 64);

    // ---- pack P -> 4 bf16x8 A-frags (k-slots of 16) ----
    bf16x8 pa[4];
    build2(S0, &pa[0]);
    build2(S1, &pa[2]);

    // ---- PV: O[32q][128d] += P[32q][64k] * V[64k][128d], B from V^T ----
    __builtin_amdgcn_s_setprio(1);
#pragma unroll
    for (int ks4 = 0; ks4 < 4; ++ks4) {
#pragma unroll
      for (int nt = 0; nt < 4; ++nt) {
        const int d = nt * 32 + l31;
        bf16x8 vb = *reinterpret_cast<const bf16x8*>(vbase + d * 128 + ((ks4 * 32 + hi * 16) ^ swz));
        O[nt] = __builtin_amdgcn_mfma_f32_32x32x16_bf16(pa[ks4], vb, O[nt], 0, 0, 0);
      }
    }
    __builtin_amdgcn_s_setprio(0);

    asm volatile("" ::: "memory");
    __builtin_amdgcn_s_barrier();    // all reads of `cur` done before next overwrite
    asm volatile("" ::: "memory");
    cur ^= 1;
  }

  // ---- write unnormalized partials + (m,l) stats ----
  float* Obase = Op + ((size_t)sp * SEQ + q0) * DH;
#pragma unroll
  for (int nt = 0; nt < 4; ++nt)
#pragma unroll
    for (int r = 0; r < 16; ++r) {
      int row = (r & 3) + 8 * (r >> 2) + 4 * hi;
      Obase[(size_t)row * DH + nt * 32 + l31] = O[nt][r];
    }
  if (lane < 32) {
    ml[(size_t)sp * (2 * SEQ) + q0 + lane]       = m;
    ml[(size_t)sp * (2 * SEQ) + SEQ + q0 + lane] = l;
  }
}

// ---------------------------------------------------------------------------
// Kernel 3: combine the NS partials (log2-domain LSE merge), float4 per thread
// ---------------------------------------------------------------------------
template <int NS>
__global__ __launch_bounds__(256) void combine_kernel(
    const float* __restrict__ Op, const float* __restrict__ ml, float* __restrict__ out)
{
  const int idx = blockIdx.x * 256 + threadIdx.x;
  const int s = idx >> 5;
  const int c = (idx & 31) * 4;
  float mv[NS], lv[NS];
  float M = -__builtin_inff();
#pragma unroll
  for (int i = 0; i < NS; ++i) {
    mv[i] = ml[(size_t)i * (2 * SEQ) + s];
    lv[i] = ml[(size_t)i * (2 * SEQ) + SEQ + s];
    M = fmaxf(M, mv[i]);
  }
  float den = 0.f;
  f32x4 num = {};
#pragma unroll
  for (int i = 0; i < NS; ++i) {
    float w = __builtin_amdgcn_exp2f(mv[i] - M);
    den += w * lv[i];
    f32x4 o = *reinterpret_cast<const f32x4*>(&Op[((size_t)i * SEQ + s) * DH + c]);
#pragma unroll
    for (int j = 0; j < 4; ++j) num[j] += w * o[j];
  }
  const float inv = 1.f / den;
  f32x4 res;
#pragma unroll
  for (int j = 0; j < 4; ++j) res[j] = num[j] * inv;
  *reinterpret_cast<f32x4*>(&out[(size_t)s * DH + c]) = res;
}

// ---------------------------------------------------------------------------
extern "C" void kernel_launch(void* const* d_in, const int* in_sizes, int n_in,
                              void* d_out, int out_size, void* d_ws, size_t ws_size,
                              hipStream_t stream) {
  const float* x  = (const float*)d_in[0];
  const float* wq = (const float*)d_in[1];
  const float* wk = (const float*)d_in[2];
  const float* wv = (const float*)d_in[3];
  float* out = (float*)d_out;

  char* ws = (char*)d_ws;
  unsigned short* qs = (unsigned short*)(ws);                       // [SEQ][DH] bf16, log2e-scaled
  unsigned short* ks = (unsigned short*)(ws + 2u * 1024 * 1024);    // [SEQ][DH] bf16
  unsigned short* vt = (unsigned short*)(ws + 4u * 1024 * 1024);    // [DH][SEQ] bf16 (V^T)
  char* base = ws + 6u * 1024 * 1024;

  qkv_kernel<<<dim3(SEQ / 128, 3), 256, 0, stream>>>(x, wq, wk, wv, qs, ks, vt);

  const size_t need8 = 6ull * 1024 * 1024 + 8ull * SEQ * DH * 4 + 8ull * 2 * SEQ * 4;
  if (ws_size >= need8) {
    float* Op = (float*)base;                                        // [8][SEQ][DH]
    float* ml = (float*)(base + 8ull * SEQ * DH * 4);                // [8][2][SEQ]
    attn_kernel<8><<<dim3(SEQ / 256, 8), 512, 0, stream>>>(qs, ks, vt, Op, ml);
    combine_kernel<8><<<SEQ * DH / 4 / 256, 256, 0, stream>>>(Op, ml, out);
  } else {
    float* Op = (float*)base;                                        // [4][SEQ][DH]
    float* ml = (float*)(base + 4ull * SEQ * DH * 4);                // [4][2][SEQ]
    attn_kernel<4><<<dim3(SEQ / 256, 4), 512, 0, stream>>>(qs, ks, vt, Op, ml);
    combine_kernel<4><<<SEQ * DH / 4 / 256, 256, 0, stream>>>(Op, ml, out);
  }
}

// Round 3
// 88.162 us; speedup vs baseline: 1.6425x; 1.2438x over previous
//
#include <hip/hip_runtime.h>
#include <cstdint>
#include <cstddef>

#define SEQ 8192
#define EMB 1024
#define DH  128

typedef __bf16 bf16x8 __attribute__((ext_vector_type(8)));
typedef __bf16 bf16x2 __attribute__((ext_vector_type(2)));
typedef float  f32x4  __attribute__((ext_vector_type(4)));
typedef float  f32x16 __attribute__((ext_vector_type(16)));
typedef uint32_t u32x4 __attribute__((ext_vector_type(4)));
typedef unsigned short u16x8 __attribute__((ext_vector_type(8)));

// Q pre-scale folded into wq: log2(e)/sqrt(128); softmax then uses v_exp_f32 (2^x) directly
static constexpr float QSCALE = (float)(1.4426950408889634 / 11.313708498984760);

// fp32 -> bf16 round-to-nearest-even
__device__ __forceinline__ unsigned short f2bf(float f) {
  uint32_t u = __builtin_bit_cast(uint32_t, f);
  u += 0x7FFFu + ((u >> 16) & 1u);
  return (unsigned short)(u >> 16);
}

// async global->LDS, 16B per lane; dst wave-uniform base (HW adds lane*16)
#define GLD_LDS16(gsrc, ldst) \
  __builtin_amdgcn_global_load_lds((__attribute__((address_space(1))) void*)(gsrc), \
                                   (__attribute__((address_space(3))) void*)(ldst), 16, 0, 0)

// ---------------------------------------------------------------------------
// Kernel 0: convert. blocks [0,2048): x f32 -> xb bf16 (vectorized).
// blocks [2048,2060): weights -> wt[3][128][1024] bf16, transposed, wq scaled.
// ---------------------------------------------------------------------------
__global__ __launch_bounds__(256) void convert_kernel(
    const float* __restrict__ x,
    const float* __restrict__ wq, const float* __restrict__ wk, const float* __restrict__ wv,
    unsigned short* __restrict__ xb, unsigned short* __restrict__ wt)
{
  const int bid = blockIdx.x;
  const int t = threadIdx.x;
  if (bid < 2048) {
    size_t e = (size_t)bid * 4096 + (size_t)t * 16;
#pragma unroll
    for (int i = 0; i < 2; ++i) {
      float4 a = *reinterpret_cast<const float4*>(x + e + i * 8);
      float4 b = *reinterpret_cast<const float4*>(x + e + i * 8 + 4);
      u16x8 o = { f2bf(a.x), f2bf(a.y), f2bf(a.z), f2bf(a.w),
                  f2bf(b.x), f2bf(b.y), f2bf(b.z), f2bf(b.w) };
      *reinterpret_cast<u16x8*>(xb + e + i * 8) = o;
    }
  } else {
    const int which = (bid - 2048) >> 2;
    const int k = ((bid - 2048) & 3) * 256 + t;
    const float* w = (which == 0) ? wq : ((which == 1) ? wk : wv);
    const float scl = (which == 0) ? QSCALE : 1.0f;
#pragma unroll
    for (int n = 0; n < 128; n += 4) {
      float4 v = *reinterpret_cast<const float4*>(w + (size_t)k * DH + n);
      wt[((size_t)which * DH + n + 0) * EMB + k] = f2bf(v.x * scl);
      wt[((size_t)which * DH + n + 1) * EMB + k] = f2bf(v.y * scl);
      wt[((size_t)which * DH + n + 2) * EMB + k] = f2bf(v.z * scl);
      wt[((size_t)which * DH + n + 3) * EMB + k] = f2bf(v.w * scl);
    }
  }
}

// ---------------------------------------------------------------------------
// Kernel 1: QKV GEMM (bf16): C[8192][128] per blockIdx.y matrix.
// Tile 64 rows x 128 cols, BK=64, dbuf global_load_lds + vmcnt(6).
// 4 waves (2x2), wave = 32 rows x 64 cols, 32x32x16 MFMA.
// y==2 (V) written transposed as vt[d][seq] via LDS epilogue.
// ---------------------------------------------------------------------------
__global__ __launch_bounds__(256) void qkv_gemm(
    const unsigned short* __restrict__ xb, const unsigned short* __restrict__ wt,
    unsigned short* __restrict__ qs, unsigned short* __restrict__ ks,
    unsigned short* __restrict__ vt)
{
  __shared__ char LDS[49152];
  char* A0 = LDS;                       // [2][64*128B]  8KB each
  char* B0 = LDS + 16384;               // [2][128*128B] 16KB each
  unsigned short* T = (unsigned short*)LDS;   // [128][72] epilogue alias (18.4KB)

  const int t    = threadIdx.x;
  const int lane = t & 63;
  const int wid  = t >> 6;
  const int wr   = wid >> 1, wc = wid & 1;
  const int l31  = lane & 31;
  const int hi   = lane >> 5;
  const int row0 = blockIdx.x * 64;
  const int which = blockIdx.y;

  const char* xc  = (const char*)xb;
  const char* wtc = (const char*)(wt + (size_t)which * DH * EMB);

  f32x16 acc[2] = {};

  auto STAGE = [&](int buf, int k0) {
    // A tile: 64 rows x 128B, 2 issues
#pragma unroll
    for (int i = 0; i < 2; ++i) {
      int bidx = i * 4096 + t * 16;
      int row = bidx >> 7, off = bidx & 127;
      const char* src = xc + (size_t)(row0 + row) * (EMB * 2) + k0 * 2 + (off ^ ((row & 7) << 4));
      GLD_LDS16(src, A0 + buf * 8192 + i * 4096 + wid * 1024);
    }
    // B tile: 128 n-rows x 128B, 4 issues
#pragma unroll
    for (int i = 0; i < 4; ++i) {
      int bidx = i * 4096 + t * 16;
      int n = bidx >> 7, off = bidx & 127;
      const char* src = wtc + (size_t)n * (EMB * 2) + k0 * 2 + (off ^ ((n & 7) << 4));
      GLD_LDS16(src, B0 + buf * 16384 + i * 4096 + wid * 1024);
    }
  };

  STAGE(0, 0);
  int cur = 0;
  for (int it = 0; it < EMB / 64; ++it) {
    if (it + 1 < EMB / 64) {
      STAGE(cur ^ 1, (it + 1) * 64);
      asm volatile("s_waitcnt vmcnt(6)" ::: "memory");   // my 6 loads for tile `it` done
    } else {
      asm volatile("s_waitcnt vmcnt(0)" ::: "memory");
    }
    __builtin_amdgcn_s_barrier();
    asm volatile("" ::: "memory");

    const char* Ab = A0 + cur * 8192;
    const char* Bb = B0 + cur * 16384;
    const int ar   = wr * 32 + l31;
    const int aswz = (l31 & 7) << 4;

    __builtin_amdgcn_s_setprio(1);
#pragma unroll
    for (int kk = 0; kk < 4; ++kk) {
      bf16x8 af = *reinterpret_cast<const bf16x8*>(Ab + ar * 128 + ((kk * 32 + hi * 16) ^ aswz));
#pragma unroll
      for (int nt = 0; nt < 2; ++nt) {
        const int n = wc * 64 + nt * 32 + l31;
        bf16x8 bf = *reinterpret_cast<const bf16x8*>(Bb + n * 128 + ((kk * 32 + hi * 16) ^ ((n & 7) << 4)));
        acc[nt] = __builtin_amdgcn_mfma_f32_32x32x16_bf16(af, bf, acc[nt], 0, 0, 0);
      }
    }
    __builtin_amdgcn_s_setprio(0);

    asm volatile("" ::: "memory");
    __builtin_amdgcn_s_barrier();   // all reads of `cur` done before next overwrite
    asm volatile("" ::: "memory");
    cur ^= 1;
  }

  // ---- epilogue. C/D map: col = l31, row = (r&3) + 8*(r>>2) + 4*hi ----
  if (which < 2) {
    unsigned short* dst = (which == 0) ? qs : ks;
#pragma unroll
    for (int nt = 0; nt < 2; ++nt)
#pragma unroll
      for (int r = 0; r < 16; ++r) {
        int row = row0 + wr * 32 + (r & 3) + 8 * (r >> 2) + 4 * hi;
        dst[(size_t)row * DH + wc * 64 + nt * 32 + l31] = f2bf(acc[nt][r]);
      }
  } else {
    __syncthreads();   // staging LDS dead; alias as T
#pragma unroll
    for (int nt = 0; nt < 2; ++nt)
#pragma unroll
      for (int r = 0; r < 16; ++r) {
        int d  = wc * 64 + nt * 32 + l31;
        int rl = wr * 32 + (r & 3) + 8 * (r >> 2) + 4 * hi;
        T[d * 72 + rl] = f2bf(acc[nt][r]);
      }
    __syncthreads();
    const int d = t >> 1, half = t & 1;
#pragma unroll
    for (int i = 0; i < 4; ++i) {
      uint4 v = *reinterpret_cast<const uint4*>(&T[d * 72 + half * 32 + i * 8]);
      *reinterpret_cast<uint4*>(vt + (size_t)d * SEQ + row0 + half * 32 + i * 8) = v;
    }
  }
}

// ---------------------------------------------------------------------------
// Kernel 2: flash attention partials, 8-wave swapped-QK^T (unchanged from R2).
// ---------------------------------------------------------------------------
template <int NS>
__global__ __launch_bounds__(512, 2) void attn_kernel(
    const unsigned short* __restrict__ qs, const unsigned short* __restrict__ ks,
    const unsigned short* __restrict__ vt,
    float* __restrict__ Op, float* __restrict__ ml)
{
  __shared__ unsigned short Ks[2][64 * 128];   // [key][d], XOR-swizzled rows
  __shared__ unsigned short Vt[2][128 * 64];   // [d][key], XOR-swizzled rows

  const int t    = threadIdx.x;
  const int lane = t & 63;
  const int wid  = t >> 6;
  const int l31  = lane & 31;
  const int hi   = lane >> 5;
  const int swz  = (lane & 7) << 4;
  const int q0   = blockIdx.x * 256 + wid * 32;
  const int sp   = blockIdx.y;

  bf16x8 qf[8];
  {
    const unsigned short* qp = qs + (size_t)(q0 + l31) * DH + hi * 8;
#pragma unroll
    for (int ds = 0; ds < 8; ++ds)
      qf[ds] = *reinterpret_cast<const bf16x8*>(qp + ds * 16);
  }

  float m = -__builtin_inff();
  float l = 0.f;
  f32x16 O[4] = {};

  const char* ksc = (const char*)ks;
  const char* vtc = (const char*)vt;
  char* ksl = (char*)&Ks[0][0];
  char* vtl = (char*)&Vt[0][0];

  constexpr int CHUNK = SEQ / NS;
  constexpr int NT = CHUNK / 64;
  const int kv_base = sp * CHUNK;

  auto STAGE = [&](int buf, int it) {
    const int kv0 = kv_base + it * 64;
#pragma unroll
    for (int rr = 0; rr < 2; ++rr) {
      int bidx = rr * 512 + t;
      int key = bidx >> 4, blk = bidx & 15;
      const char* src = ksc + (size_t)(kv0 + key) * 256 + ((blk * 16) ^ ((key & 7) << 4));
      GLD_LDS16(src, ksl + buf * 16384 + rr * 8192 + wid * 1024);
    }
#pragma unroll
    for (int rr = 0; rr < 2; ++rr) {
      int bidx = rr * 512 + t;
      int d = bidx >> 3, kb = bidx & 7;
      const char* src = vtc + (size_t)d * (SEQ * 2) + (size_t)kv0 * 2 + ((kb * 16) ^ ((d & 7) << 4));
      GLD_LDS16(src, vtl + buf * 16384 + rr * 8192 + wid * 1024);
    }
  };

  auto build2 = [&](const f32x16& P, bf16x8* fr) {
    uint32_t c[8];
#pragma unroll
    for (int i = 0; i < 8; ++i) {
      bf16x2 b2; b2[0] = (__bf16)P[2 * i]; b2[1] = (__bf16)P[2 * i + 1];
      c[i] = __builtin_bit_cast(uint32_t, b2);
    }
    uint32_t r0 = __shfl_xor(c[0], 32, 64), r1 = __shfl_xor(c[1], 32, 64);
    uint32_t r2 = __shfl_xor(c[2], 32, 64), r3 = __shfl_xor(c[3], 32, 64);
    u32x4 w0;
    w0[0] = hi ? r2 : c[0];
    w0[1] = hi ? r3 : c[1];
    w0[2] = hi ? c[2] : r0;
    w0[3] = hi ? c[3] : r1;
    uint32_t r4 = __shfl_xor(c[4], 32, 64), r5 = __shfl_xor(c[5], 32, 64);
    uint32_t r6 = __shfl_xor(c[6], 32, 64), r7 = __shfl_xor(c[7], 32, 64);
    u32x4 w1;
    w1[0] = hi ? r6 : c[4];
    w1[1] = hi ? r7 : c[5];
    w1[2] = hi ? c[6] : r4;
    w1[3] = hi ? c[7] : r5;
    fr[0] = __builtin_bit_cast(bf16x8, w0);
    fr[1] = __builtin_bit_cast(bf16x8, w1);
  };

  STAGE(0, 0);

  int cur = 0;
  for (int it = 0; it < NT; ++it) {
    if (it + 1 < NT) {
      STAGE(cur ^ 1, it + 1);
      asm volatile("s_waitcnt vmcnt(4)" ::: "memory");
    } else {
      asm volatile("s_waitcnt vmcnt(0)" ::: "memory");
    }
    __builtin_amdgcn_s_barrier();
    asm volatile("" ::: "memory");

    const char* kbase = ksl + cur * 16384;
    const char* vbase = vtl + cur * 16384;

    f32x16 S0 = {}, S1 = {};
    __builtin_amdgcn_s_setprio(1);
#pragma unroll
    for (int ds = 0; ds < 8; ++ds) {
      bf16x8 ka = *reinterpret_cast<const bf16x8*>(kbase + l31 * 256 + ((ds * 32 + hi * 16) ^ swz));
      S0 = __builtin_amdgcn_mfma_f32_32x32x16_bf16(ka, qf[ds], S0, 0, 0, 0);
    }
#pragma unroll
    for (int ds = 0; ds < 8; ++ds) {
      bf16x8 ka = *reinterpret_cast<const bf16x8*>(kbase + 8192 + l31 * 256 + ((ds * 32 + hi * 16) ^ swz));
      S1 = __builtin_amdgcn_mfma_f32_32x32x16_bf16(ka, qf[ds], S1, 0, 0, 0);
    }
    __builtin_amdgcn_s_setprio(0);

    float pm;
    {
      float a = S0[0];
#pragma unroll
      for (int r = 1; r < 16; ++r) a = fmaxf(a, S0[r]);
#pragma unroll
      for (int r = 0; r < 16; ++r) a = fmaxf(a, S1[r]);
      pm = fmaxf(a, __shfl_xor(a, 32, 64));
    }
    if (__any(pm > m + 11.0f)) {
      float mn = fmaxf(m, pm);
      float corr = __builtin_amdgcn_exp2f(m - mn);
      m = mn;
      l *= corr;
#pragma unroll
      for (int r = 0; r < 16; ++r) {
        float cr = __shfl(corr, (r & 3) + 8 * (r >> 2) + 4 * hi, 64);
#pragma unroll
        for (int nt = 0; nt < 4; ++nt) O[nt][r] *= cr;
      }
    }
    float rsum = 0.f;
#pragma unroll
    for (int r = 0; r < 16; ++r) { S0[r] = __builtin_amdgcn_exp2f(S0[r] - m); rsum += S0[r]; }
#pragma unroll
    for (int r = 0; r < 16; ++r) { S1[r] = __builtin_amdgcn_exp2f(S1[r] - m); rsum += S1[r]; }
    l += rsum + __shfl_xor(rsum, 32, 64);

    bf16x8 pa[4];
    build2(S0, &pa[0]);
    build2(S1, &pa[2]);

    __builtin_amdgcn_s_setprio(1);
#pragma unroll
    for (int ks4 = 0; ks4 < 4; ++ks4) {
#pragma unroll
      for (int nt = 0; nt < 4; ++nt) {
        const int d = nt * 32 + l31;
        bf16x8 vb = *reinterpret_cast<const bf16x8*>(vbase + d * 128 + ((ks4 * 32 + hi * 16) ^ swz));
        O[nt] = __builtin_amdgcn_mfma_f32_32x32x16_bf16(pa[ks4], vb, O[nt], 0, 0, 0);
      }
    }
    __builtin_amdgcn_s_setprio(0);

    asm volatile("" ::: "memory");
    __builtin_amdgcn_s_barrier();
    asm volatile("" ::: "memory");
    cur ^= 1;
  }

  float* Obase = Op + ((size_t)sp * SEQ + q0) * DH;
#pragma unroll
  for (int nt = 0; nt < 4; ++nt)
#pragma unroll
    for (int r = 0; r < 16; ++r) {
      int row = (r & 3) + 8 * (r >> 2) + 4 * hi;
      Obase[(size_t)row * DH + nt * 32 + l31] = O[nt][r];
    }
  if (lane < 32) {
    ml[(size_t)sp * (2 * SEQ) + q0 + lane]       = m;
    ml[(size_t)sp * (2 * SEQ) + SEQ + q0 + lane] = l;
  }
}

// ---------------------------------------------------------------------------
// Kernel 3: combine the NS partials (log2-domain LSE merge), float4 per thread
// ---------------------------------------------------------------------------
template <int NS>
__global__ __launch_bounds__(256) void combine_kernel(
    const float* __restrict__ Op, const float* __restrict__ ml, float* __restrict__ out)
{
  const int idx = blockIdx.x * 256 + threadIdx.x;
  const int s = idx >> 5;
  const int c = (idx & 31) * 4;
  float mv[NS], lv[NS];
  float M = -__builtin_inff();
#pragma unroll
  for (int i = 0; i < NS; ++i) {
    mv[i] = ml[(size_t)i * (2 * SEQ) + s];
    lv[i] = ml[(size_t)i * (2 * SEQ) + SEQ + s];
    M = fmaxf(M, mv[i]);
  }
  float den = 0.f;
  f32x4 num = {};
#pragma unroll
  for (int i = 0; i < NS; ++i) {
    float w = __builtin_amdgcn_exp2f(mv[i] - M);
    den += w * lv[i];
    f32x4 o = *reinterpret_cast<const f32x4*>(&Op[((size_t)i * SEQ + s) * DH + c]);
#pragma unroll
    for (int j = 0; j < 4; ++j) num[j] += w * o[j];
  }
  const float inv = 1.f / den;
  f32x4 res;
#pragma unroll
  for (int j = 0; j < 4; ++j) res[j] = num[j] * inv;
  *reinterpret_cast<f32x4*>(&out[(size_t)s * DH + c]) = res;
}

// ---------------------------------------------------------------------------
extern "C" void kernel_launch(void* const* d_in, const int* in_sizes, int n_in,
                              void* d_out, int out_size, void* d_ws, size_t ws_size,
                              hipStream_t stream) {
  const float* x  = (const float*)d_in[0];
  const float* wq = (const float*)d_in[1];
  const float* wk = (const float*)d_in[2];
  const float* wv = (const float*)d_in[3];
  float* out = (float*)d_out;

  char* ws = (char*)d_ws;
  const size_t MB = 1024 * 1024;
  // layout: qs(2MB) ks(2MB) vt(2MB) wt(768KB; ml aliases it later) xb(16MB; Op aliases it)
  unsigned short* qs = (unsigned short*)(ws);
  unsigned short* ks = (unsigned short*)(ws + 2 * MB);
  unsigned short* vt = (unsigned short*)(ws + 4 * MB);
  unsigned short* wt = (unsigned short*)(ws + 6 * MB);               // [3][128][1024] bf16, 768KB
  float* ml          = (float*)(ws + 6 * MB);                        // aliases wt (wt dead post-GEMM)
  unsigned short* xb = (unsigned short*)(ws + 6 * MB + 768 * 1024);  // [8192][1024] bf16, 16MB
  float* Op          = (float*)xb;                                   // aliases xb (xb dead post-GEMM)

  convert_kernel<<<2048 + 12, 256, 0, stream>>>(x, wq, wk, wv, xb, wt);
  qkv_gemm<<<dim3(SEQ / 64, 3), 256, 0, stream>>>(xb, wt, qs, ks, vt);

  const size_t base = 6 * MB + 768 * 1024;
  if (ws_size >= base + 32ull * MB + 8ull * 2 * SEQ * 4) {
    attn_kernel<8><<<dim3(SEQ / 256, 8), 512, 0, stream>>>(qs, ks, vt, Op, ml);
    combine_kernel<8><<<SEQ * DH / 4 / 256, 256, 0, stream>>>(Op, ml, out);
  } else {
    attn_kernel<4><<<dim3(SEQ / 256, 4), 512, 0, stream>>>(qs, ks, vt, Op, ml);
    combine_kernel<4><<<SEQ * DH / 4 / 256, 256, 0, stream>>>(Op, ml, out);
  }
}